// Round 3
// baseline (76.414 us; speedup 1.0000x reference)
//
#include <hip/hip_runtime.h>
#include <stdint.h>

#define LL   2048
#define DD   256
#define SLOTS 64
#define MN   192
#define PT   8192          // B*L

typedef _Float16 half8 __attribute__((ext_vector_type(8)));
typedef float    f32x4 __attribute__((ext_vector_type(4)));

// ---------------- single fused kernel: frag build + score MFMA + argmax + select MFMA ----
// grid 256 x 768 thr (12 waves). Block -> 32 output rows; 48-slot window (34 real).
// No workspace: mem (196KB) is re-laid-out inside the kernel each block.
//   aS frags (score GEMM A, hi/lo f16): per-wave in REGISTERS (wave w = mn-tile w).
//   bG frags (select GEMM B, hi f16):   in LDS (96KB), built by gather+ds_write_b128.
//   scores (f32) OVERLAY the dead x-frag region after phase B (extra barrier).
__global__ __launch_bounds__(768, 3) void fused_kernel(
    const float* __restrict__ x, const float* __restrict__ mem,
    const float* __restrict__ bias,
    float* __restrict__ out)
{
    __shared__ __align__(16) char xbuf[49152];            // 48KB: xfh(24K)+xfl(24K), later scores
    __shared__ __align__(16) _Float16 bGs[16 * 6 * 64 * 8]; // 96KB select-GEMM B-frags
    __shared__ float    biasS[MN];
    __shared__ uint32_t selS[32 * 6];
    // total ~145.5KB, 1 block/CU (grid == 256)

    _Float16* xfh = (_Float16*)xbuf;            // 24KB
    _Float16* xfl = (_Float16*)(xbuf + 24576);  // 24KB
    float*    scores = (float*)xbuf;            // 26.25KB, valid after phase B

    const int p0   = blockIdx.x * 32;
    const int tid  = threadIdx.x;
    const int lane = tid & 63;
    const int w    = tid >> 6;          // 0..11
    const int q    = lane >> 4, col = lane & 15;
    const int tm   = w;                 // mn-tile owned by this wave (score GEMM)

    if (tid < MN) {
        const int m = tid & 63, n = tid >> 6;
        biasS[tid] = bias[m * 3 + n];    // permute to n-major
    }

    // ---- A1: gather mem -> bG LDS frags (hi f16). 96 (td,c2) combos, 8 per wave. ----
    // lane = q2*16+n2; per combo each lane loads 8 scalars (j2=0..7) and writes one half8.
    float gv[8][8];
#pragma unroll
    for (int k = 0; k < 8; ++k) {
        const int combo = w + k * 12;    // 0..95
        const int td = combo / 6, c2 = combo - td * 6;
        const int q2 = lane >> 4, n2 = lane & 15;
#pragma unroll
        for (int j = 0; j < 8; ++j) {
            const int mnp = c2 * 32 + q2 * 8 + j;       // n-major mn index
            const int n = mnp >> 6, m = mnp & 63;
            gv[k][j] = mem[(size_t)(m * 3 + n) * DD + td * 16 + n2];
        }
    }

    // ---- A2: stage 48-slot x window -> f16 hi/lo B-frags in LDS ----
#pragma unroll
    for (int kk = 0; kk < 2; ++kk) {
        const int idx = tid + kk * 768;  // 0..1535
        const int rr  = idx >> 5;        // slot 0..47
        const int ch  = idx & 31;        // 8-d chunk
        int g = p0 - 2 + rr;
        g = g < 0 ? 0 : (g > PT - 1 ? PT - 1 : g);
        const float4* xr = (const float4*)(x + (size_t)g * DD + ch * 8);
        const float4 u = xr[0];
        const float4 v = xr[1];
        float f[8] = {u.x, u.y, u.z, u.w, v.x, v.y, v.z, v.w};
        half8 hi, lo;
#pragma unroll
        for (int j = 0; j < 8; ++j) {
            const _Float16 hh = (_Float16)f[j];
            hi[j] = hh;
            lo[j] = (_Float16)(f[j] - (float)hh);
        }
        const int c = ch >> 2, qq = ch & 3;
        const int pt = rr >> 4, lr = rr & 15;
        const int base = ((pt * 8 + c) * 64 + qq * 16 + lr) * 8;
        *(half8*)(xfh + base) = hi;
        *(half8*)(xfl + base) = lo;
    }

    // ---- A1b: convert + write bG frags (frees gv regs) ----
#pragma unroll
    for (int k = 0; k < 8; ++k) {
        const int combo = w + k * 12;
        const int td = combo / 6, c2 = combo - td * 6;
        half8 hv;
#pragma unroll
        for (int j = 0; j < 8; ++j) hv[j] = (_Float16)gv[k][j];
        *(half8*)(bGs + (size_t)((td * 6 + c2) * 64 + lane) * 8) = hv;
    }

    // ---- A3: build aS A-frags (hi/lo) in registers for tile tm (2 rounds of 4 chunks) ----
    half8 ah[8], al[8];
    {
        const int r = lane & 15;         // row within tile
        const int mnp = tm * 16 + r;
        const int n = mnp >> 6, m = mnp & 63;
        const float* rowp = mem + (size_t)(m * 3 + n) * DD;
#pragma unroll
        for (int half = 0; half < 2; ++half) {
            float4 u[4], v[4];
#pragma unroll
            for (int ci = 0; ci < 4; ++ci) {
                const int c = half * 4 + ci;
                const float4* ap = (const float4*)(rowp + c * 32 + q * 8);
                u[ci] = ap[0];
                v[ci] = ap[1];
            }
#pragma unroll
            for (int ci = 0; ci < 4; ++ci) {
                const int c = half * 4 + ci;
                float f[8] = {u[ci].x, u[ci].y, u[ci].z, u[ci].w,
                              v[ci].x, v[ci].y, v[ci].z, v[ci].w};
#pragma unroll
                for (int j = 0; j < 8; ++j) {
                    const _Float16 hh = (_Float16)f[j];
                    ah[c][j] = hh;
                    al[c][j] = (_Float16)(f[j] - (float)hh);
                }
            }
        }
    }
    __syncthreads();   // (1) xf + bG ready

    // ---- Phase B: score GEMM, A from regs, 3 p-tiles, depth-1 LDS pipeline ----
    f32x4 acc[3];
#pragma unroll
    for (int p = 0; p < 3; ++p) acc[p] = (f32x4){0.f, 0.f, 0.f, 0.f};
    {
        half8 bh[2][3], bl[2][3];
#pragma unroll
        for (int p = 0; p < 3; ++p) {
            const int base = ((p * 8 + 0) * 64 + lane) * 8;
            bh[0][p] = *(const half8*)(xfh + base);
            bl[0][p] = *(const half8*)(xfl + base);
        }

#pragma unroll
        for (int c = 0; c < 8; ++c) {
            const int cur = c & 1, nxt = cur ^ 1;
            if (c < 7) {
#pragma unroll
                for (int p = 0; p < 3; ++p) {
                    const int base = ((p * 8 + c + 1) * 64 + lane) * 8;
                    bh[nxt][p] = *(const half8*)(xfh + base);
                    bl[nxt][p] = *(const half8*)(xfl + base);
                }
            }
#pragma unroll
            for (int p = 0; p < 3; ++p) {
                acc[p] = __builtin_amdgcn_mfma_f32_16x16x32_f16(ah[c], bh[cur][p], acc[p], 0, 0, 0);
                acc[p] = __builtin_amdgcn_mfma_f32_16x16x32_f16(ah[c], bl[cur][p], acc[p], 0, 0, 0);
                acc[p] = __builtin_amdgcn_mfma_f32_16x16x32_f16(al[c], bh[cur][p], acc[p], 0, 0, 0);
            }
        }
    }
    __syncthreads();   // (2) xf dead -> scores may overlay

    // ---- store scores (f32, stride 35) into overlay; window cols 0..33 ----
#pragma unroll
    for (int p = 0; p < 3; ++p) {
        const int wp = p * 16 + col;
        if (wp < 34) {
#pragma unroll
            for (int r = 0; r < 4; ++r)
                scores[(tm * 16 + q * 4 + r) * 35 + wp] = acc[p][r];
        }
    }
    __syncthreads();   // (3) scores ready

    // ---- Phase C: wave-parallel argmax (lane = slot m) + ballot mask build ----
    for (int pl = w; pl < 32; pl += 12) {
        const int m = lane;
        const int p = p0 + pl;
        const int l = p & (LL - 1);
        const float v0 = ((l >= 2) ? scores[(      m) * 35 + pl + 0] : 0.f) + biasS[      m];
        const float v1 = ((l >= 1) ? scores[( 64 + m) * 35 + pl + 1] : 0.f) + biasS[ 64 + m];
        const float v2 =             scores[(128 + m) * 35 + pl + 2]        + biasS[128 + m];
        int bn = 0; float bv = v0;
        if (v1 > bv) { bv = v1; bn = 1; }
        if (v2 > bv) { bv = v2; bn = 2; }
        const unsigned long long b0 = __ballot(bn == 0);
        const unsigned long long b1 = __ballot(bn == 1);
        const unsigned long long b2 = __ballot(bn == 2);
        if (lane < 6) {
            const unsigned long long B = (lane >> 1) == 0 ? b0 : ((lane >> 1) == 1 ? b1 : b2);
            selS[pl * 6 + lane] = (uint32_t)(B >> ((lane & 1) * 32));
        }
    }
    __syncthreads();   // (4) selS ready

    // ---- Phase D: select GEMM (f16 hi only), B from LDS, tasks t = w, w+12, w+24 ----
    {
        const _Float16 ONE = (_Float16)1.f, ZERO = (_Float16)0.f;
        const int qb = q * 8;
#pragma unroll
        for (int ti = 0; ti < 3; ++ti) {
            const int t = w + ti * 12;
            if (t < 32) {
                const int pt = t >> 4, td = t & 15;
                uint32_t sw[6];
#pragma unroll
                for (int c = 0; c < 6; ++c) sw[c] = selS[(pt * 16 + col) * 6 + c];

                f32x4 acc2 = (f32x4){0.f, 0.f, 0.f, 0.f};
                half8 mg[2];
                mg[0] = *(const half8*)(bGs + (size_t)((td * 6 + 0) * 64 + lane) * 8);
#pragma unroll
                for (int c = 0; c < 6; ++c) {
                    const int cur = c & 1, nxt = cur ^ 1;
                    if (c < 5)
                        mg[nxt] = *(const half8*)(bGs + (size_t)((td * 6 + c + 1) * 64 + lane) * 8);
                    half8 sel;
#pragma unroll
                    for (int j = 0; j < 8; ++j)
                        sel[j] = ((sw[c] >> (qb + j)) & 1u) ? ONE : ZERO;
                    acc2 = __builtin_amdgcn_mfma_f32_16x16x32_f16(sel, mg[cur], acc2, 0, 0, 0);
                }

#pragma unroll
                for (int r = 0; r < 4; ++r)
                    out[(size_t)(p0 + pt * 16 + q * 4 + r) * DD + td * 16 + col] = acc2[r];
            }
        }
    }
}

extern "C" void kernel_launch(void* const* d_in, const int* in_sizes, int n_in,
                              void* d_out, int out_size, void* d_ws, size_t ws_size,
                              hipStream_t stream) {
    (void)in_sizes; (void)n_in; (void)out_size; (void)d_ws; (void)ws_size;
    const float* x    = (const float*)d_in[0];
    const float* mem  = (const float*)d_in[1];
    const float* bias = (const float*)d_in[2];
    float* out = (float*)d_out;

    fused_kernel<<<PT / 32, 768, 0, stream>>>(x, mem, bias, out);
}

// Round 4
// 72.364 us; speedup vs baseline: 1.0560x; 1.0560x over previous
//
#include <hip/hip_runtime.h>
#include <stdint.h>

#define LL   2048
#define DD   256
#define SLOTS 64
#define MN   192
#define PT   8192          // B*L

typedef _Float16 half8 __attribute__((ext_vector_type(8)));
typedef float    f32x4 __attribute__((ext_vector_type(4)));

#define FRAG_ELEMS (MN * DD)   // 49152 f16 elems per frag array

// ---------------- K0: fragment prep ----------------
// mn index is n-major (mn' = n*64 + m) so phase-C selection masks can be built
// with wave ballots (lane = m). aS_h/aS_l: score-GEMM A-frags; bG_h: select-GEMM B-frags.
__global__ __launch_bounds__(256) void prep_kernel(
    const float* __restrict__ mem,
    _Float16* __restrict__ aS_h, _Float16* __restrict__ aS_l,
    _Float16* __restrict__ bG_h)
{
    const int e = blockIdx.x * 256 + threadIdx.x;   // grid 192 -> 49152
    const int mnp = e >> 8;                          // n-major mn index
    const int d   = e & 255;
    const int n = mnp >> 6, m = mnp & 63;
    const float v = mem[((m * 3 + n) << 8) + d];
    const _Float16 h  = (_Float16)v;
    const _Float16 lo = (_Float16)(v - (float)h);

    // score GEMM A-frags: tiles of 16 mn', K-chunks of 32 d
    {
        const int tm = mnp >> 4, r = mnp & 15;
        const int c = d >> 5, q = (d >> 3) & 3, j = d & 7;
        const int i1 = ((tm * 8 + c) * 64 + (q * 16 + r)) * 8 + j;
        aS_h[i1] = h; aS_l[i1] = lo;
    }
    // select GEMM B-frags: K-chunks of 32 mn', d-tiles of 16
    {
        const int c2 = mnp >> 5, q2 = (mnp >> 3) & 3, j2 = mnp & 7;
        const int td = d >> 4, n2 = d & 15;
        const int i2 = ((td * 6 + c2) * 64 + (q2 * 16 + n2)) * 8 + j2;
        bG_h[i2] = h;
    }
}

// ---------------- K1: fused score MFMA + argmax + select MFMA ----------------
// grid 256 x 768 thr (12 waves). Block -> 32 output rows; 34-slot staged window.
// Phase B: wave w owns tm-tile w (A-frags streamed once per CU), all 3 p-tiles.
// Phase C: pl = w, w+12, w+24 (ballot masks, lane = slot m).
// Phase D: B-frags from LDS (coalesced-staged in phase A), tasks t = w, w+12, w+24.
__global__ __launch_bounds__(768, 3) void fused_kernel(
    const float* __restrict__ x, const float* __restrict__ bias,
    const _Float16* __restrict__ aS_h, const _Float16* __restrict__ aS_l,
    const _Float16* __restrict__ bG_h,
    float* __restrict__ out)
{
    __shared__ __align__(16) char xbuf[49152];               // xfh(24K)+xfl(24K); later scores
    __shared__ __align__(16) _Float16 bGs[16 * 6 * 64 * 8];  // 96KB select-GEMM B-frags
    __shared__ float    biasS[MN];
    __shared__ uint32_t selS[32 * 6];
    // total ~145.5KB, 1 block/CU (grid == 256)

    _Float16* xfh = (_Float16*)xbuf;            // 24KB
    _Float16* xfl = (_Float16*)(xbuf + 24576);  // 24KB
    float*    scores = (float*)xbuf;            // 26.25KB, overlays xf after phase B

    const int p0   = blockIdx.x * 32;
    const int tid  = threadIdx.x;
    const int lane = tid & 63;
    const int w    = tid >> 6;          // 0..11
    const int q    = lane >> 4, col = lane & 15;
    const int tm   = w;                 // mn-tile owned by this wave (score GEMM)

    // ---- prefetch phase-B A-frags (c=0) before any barrier ----
    half8 ah[2], al[2];
    {
        const size_t off = (size_t)((tm * 8 + 0) * 64 + lane) * 8;
        ah[0] = *(const half8*)(aS_h + off);
        al[0] = *(const half8*)(aS_l + off);
    }

    if (tid < MN) {
        const int m = tid & 63, n = tid >> 6;
        biasS[tid] = bias[m * 3 + n];    // permute to n-major
    }

    // ---- Phase A0: stage bG frags -> LDS (coalesced linear copy, 8 x b128 per thread) ----
    {
        const half8* src = (const half8*)bG_h;
        half8*       dst = (half8*)bGs;
#pragma unroll
        for (int i = 0; i < 8; ++i)
            dst[tid + i * 768] = src[tid + i * 768];
    }

    // ---- Phase A1: stage x window slots 0..33 -> f16 hi/lo B-frags in LDS ----
    // slot rr holds global row clamp(p0-2+rr); slots 34..47 left stale (their score
    // columns are never stored). 34*32 = 1088 thread-iters.
#pragma unroll
    for (int kk = 0; kk < 2; ++kk) {
        const int idx = tid + kk * 768;  // 0..1535
        if (idx < 1088) {
            const int rr  = idx >> 5;        // slot 0..33
            const int ch  = idx & 31;        // 8-d chunk
            int g = p0 - 2 + rr;
            g = g < 0 ? 0 : g;
            const float4* xr = (const float4*)(x + (size_t)g * DD + ch * 8);
            const float4 u = xr[0];
            const float4 v = xr[1];
            float f[8] = {u.x, u.y, u.z, u.w, v.x, v.y, v.z, v.w};
            half8 hi, lo;
#pragma unroll
            for (int j = 0; j < 8; ++j) {
                const _Float16 hh = (_Float16)f[j];
                hi[j] = hh;
                lo[j] = (_Float16)(f[j] - (float)hh);
            }
            const int c = ch >> 2, qq = ch & 3;
            const int pt = rr >> 4, lr = rr & 15;
            const int base = ((pt * 8 + c) * 64 + qq * 16 + lr) * 8;
            *(half8*)(xfh + base) = hi;
            *(half8*)(xfl + base) = lo;
        }
    }
    __syncthreads();   // (1) xf + bGs ready

    // ---- Phase B: score GEMM, A from global (depth-1), B from LDS, 3 p-tiles ----
    f32x4 acc[3];
#pragma unroll
    for (int p = 0; p < 3; ++p) acc[p] = (f32x4){0.f, 0.f, 0.f, 0.f};
    {
        half8 bh[2][3], bl[2][3];
#pragma unroll
        for (int p = 0; p < 3; ++p) {
            const int base = ((p * 8 + 0) * 64 + lane) * 8;
            bh[0][p] = *(const half8*)(xfh + base);
            bl[0][p] = *(const half8*)(xfl + base);
        }

#pragma unroll
        for (int c = 0; c < 8; ++c) {
            const int cur = c & 1, nxt = cur ^ 1;
            if (c < 7) {
                const size_t off = (size_t)((tm * 8 + c + 1) * 64 + lane) * 8;
                ah[nxt] = *(const half8*)(aS_h + off);
                al[nxt] = *(const half8*)(aS_l + off);
#pragma unroll
                for (int p = 0; p < 3; ++p) {
                    const int base = ((p * 8 + c + 1) * 64 + lane) * 8;
                    bh[nxt][p] = *(const half8*)(xfh + base);
                    bl[nxt][p] = *(const half8*)(xfl + base);
                }
            }
#pragma unroll
            for (int p = 0; p < 3; ++p) {
                acc[p] = __builtin_amdgcn_mfma_f32_16x16x32_f16(ah[cur], bh[cur][p], acc[p], 0, 0, 0);
                acc[p] = __builtin_amdgcn_mfma_f32_16x16x32_f16(ah[cur], bl[cur][p], acc[p], 0, 0, 0);
                acc[p] = __builtin_amdgcn_mfma_f32_16x16x32_f16(al[cur], bh[cur][p], acc[p], 0, 0, 0);
            }
        }
    }
    __syncthreads();   // (2) xf dead -> scores may overlay

    // ---- store scores (f32, stride 35) into overlay; window cols 0..33 ----
#pragma unroll
    for (int p = 0; p < 3; ++p) {
        const int wp = p * 16 + col;
        if (wp < 34) {
#pragma unroll
            for (int r = 0; r < 4; ++r)
                scores[(tm * 16 + q * 4 + r) * 35 + wp] = acc[p][r];
        }
    }
    __syncthreads();   // (3) scores ready

    // ---- Phase C: wave-parallel argmax (lane = slot m) + ballot mask build ----
    for (int pl = w; pl < 32; pl += 12) {
        const int m = lane;
        const int p = p0 + pl;
        const int l = p & (LL - 1);
        const float v0 = ((l >= 2) ? scores[(      m) * 35 + pl + 0] : 0.f) + biasS[      m];
        const float v1 = ((l >= 1) ? scores[( 64 + m) * 35 + pl + 1] : 0.f) + biasS[ 64 + m];
        const float v2 =             scores[(128 + m) * 35 + pl + 2]        + biasS[128 + m];
        int bn = 0; float bv = v0;
        if (v1 > bv) { bv = v1; bn = 1; }
        if (v2 > bv) { bv = v2; bn = 2; }
        const unsigned long long b0 = __ballot(bn == 0);
        const unsigned long long b1 = __ballot(bn == 1);
        const unsigned long long b2 = __ballot(bn == 2);
        if (lane < 6) {
            const unsigned long long B = (lane >> 1) == 0 ? b0 : ((lane >> 1) == 1 ? b1 : b2);
            selS[pl * 6 + lane] = (uint32_t)(B >> ((lane & 1) * 32));
        }
    }
    __syncthreads();   // (4) selS ready

    // ---- Phase D: select GEMM (f16 hi only), B from LDS, tasks t = w, w+12, w+24 ----
    {
        const _Float16 ONE = (_Float16)1.f, ZERO = (_Float16)0.f;
        const int qb = q * 8;
#pragma unroll
        for (int ti = 0; ti < 3; ++ti) {
            const int t = w + ti * 12;
            if (t < 32) {
                const int pt = t >> 4, td = t & 15;
                uint32_t sw[6];
#pragma unroll
                for (int c = 0; c < 6; ++c) sw[c] = selS[(pt * 16 + col) * 6 + c];

                f32x4 acc2 = (f32x4){0.f, 0.f, 0.f, 0.f};
                half8 mg[2];
                mg[0] = *(const half8*)(bGs + (size_t)((td * 6 + 0) * 64 + lane) * 8);
#pragma unroll
                for (int c = 0; c < 6; ++c) {
                    const int cur = c & 1, nxt = cur ^ 1;
                    if (c < 5)
                        mg[nxt] = *(const half8*)(bGs + (size_t)((td * 6 + c + 1) * 64 + lane) * 8);
                    half8 sel;
#pragma unroll
                    for (int j = 0; j < 8; ++j)
                        sel[j] = ((sw[c] >> (qb + j)) & 1u) ? ONE : ZERO;
                    acc2 = __builtin_amdgcn_mfma_f32_16x16x32_f16(sel, mg[cur], acc2, 0, 0, 0);
                }

#pragma unroll
                for (int r = 0; r < 4; ++r)
                    out[(size_t)(p0 + pt * 16 + q * 4 + r) * DD + td * 16 + col] = acc2[r];
            }
        }
    }
}

extern "C" void kernel_launch(void* const* d_in, const int* in_sizes, int n_in,
                              void* d_out, int out_size, void* d_ws, size_t ws_size,
                              hipStream_t stream) {
    (void)in_sizes; (void)n_in; (void)out_size; (void)ws_size;
    const float* x    = (const float*)d_in[0];
    const float* mem  = (const float*)d_in[1];
    const float* bias = (const float*)d_in[2];
    float* out = (float*)d_out;

    _Float16* aS_h = (_Float16*)d_ws;
    _Float16* aS_l = aS_h + FRAG_ELEMS;
    _Float16* bG_h = aS_l + FRAG_ELEMS;

    prep_kernel<<<FRAG_ELEMS / 256, 256, 0, stream>>>(mem, aS_h, aS_l, bG_h);
    fused_kernel<<<PT / 32, 768, 0, stream>>>(x, bias, aS_h, aS_l, bG_h, out);
}